// Round 1
// baseline (2487.836 us; speedup 1.0000x reference)
//
#include <hip/hip_runtime.h>

#define F_ 513
#define M_ 8
#define T_ 2048
#define K_ 2
#define NITER 20
#define REGC 1e-6
#define EPSR 1e-10
#define TOLC 1e-5

typedef double2 cd;
__device__ __forceinline__ cd cmk(double r, double i){ cd z; z.x=r; z.y=i; return z; }
__device__ __forceinline__ cd cadd(cd a, cd b){ return cmk(a.x+b.x, a.y+b.y); }
__device__ __forceinline__ cd csub(cd a, cd b){ return cmk(a.x-b.x, a.y-b.y); }
__device__ __forceinline__ cd cmul(cd a, cd b){ return cmk(a.x*b.x - a.y*b.y, a.x*b.y + a.y*b.x); }
__device__ __forceinline__ cd cconj(cd a){ return cmk(a.x, -a.y); }
__device__ __forceinline__ cd cdiv(cd a, cd b){
  double d = b.x*b.x + b.y*b.y;
  return cmk((a.x*b.x + a.y*b.y)/d, (a.y*b.x - a.x*b.y)/d);
}
__device__ __forceinline__ double cabs2(cd a){ return a.x*a.x + a.y*a.y; }
__device__ __forceinline__ cd shflc(cd v, int l){
  cd r; r.x = __shfl(v.x, l, 64); r.y = __shfl(v.y, l, 64); return r;
}
__device__ __forceinline__ cd sel8(const cd x[8], int idx){
  cd r = x[0];
  #pragma unroll
  for (int q=1;q<8;++q) if (idx==q) r = x[q];
  return r;
}

// pack X (M,T,F,2) -> Xc (F,M,T) complex float2
__global__ __launch_bounds__(256) void pack_kernel(const float2* __restrict__ Xin, float2* __restrict__ Xc){
  int idx = blockIdx.x*256 + threadIdx.x;
  if (idx >= F_*M_*T_) return;
  int t = idx & (T_-1);
  int fm = idx >> 11;
  int m = fm & 7;
  int f = fm >> 3;
  Xc[idx] = Xin[((size_t)(m*T_ + t))*F_ + f];
}

// W init: diag(1,1,-1,-1,-1,-1,-1,-1)
__global__ __launch_bounds__(256) void winit_kernel(float2* __restrict__ W){
  int idx = blockIdx.x*256 + threadIdx.x;
  if (idx >= F_*64) return;
  int l = idx & 63; int i = l>>3, j = l&7;
  float v = (i==j) ? (i < K_ ? 1.f : -1.f) : 0.f;
  float2 o; o.x = v; o.y = 0.f;
  W[idx] = o;
}

__device__ const int PMt[36] = {0,0,0,0,0,0,0,0,1,1,1,1,1,1,1,2,2,2,2,2,2,3,3,3,3,3,4,4,4,4,5,5,5,6,6,7};
__device__ const int PNt[36] = {0,1,2,3,4,5,6,7,1,2,3,4,5,6,7,2,3,4,5,6,7,3,4,5,6,7,4,5,6,7,5,6,7,6,7,7};

// MODE 0: C[f] = X X^H / T   (outC -> C, double2, F*64)
// MODE 1: V[k,f] = sum_t w[k,t] x x^H / T (outC -> V, double2, 2*F*64)
template<int MODE>
__global__ __launch_bounds__(256) void cov_kernel(const float2* __restrict__ Xc, const float* __restrict__ wts,
                                                  cd* __restrict__ outC, const int* __restrict__ done){
  if (MODE == 1 && *(volatile const int*)done) return;
  __shared__ float2 xs[8][512];
  __shared__ float wsm[2][512];
  int f = blockIdx.x;
  int tid = threadIdx.x;
  int wave = tid >> 6, lane = tid & 63;
  double a0r[9], a0i[9], a1r[9], a1i[9];
  #pragma unroll
  for (int pi=0; pi<9; ++pi){ a0r[pi]=0; a0i[pi]=0; a1r[pi]=0; a1i[pi]=0; }
  for (int c=0; c<4; ++c){
    for (int idx=tid; idx<8*512; idx+=256){
      int m = idx >> 9, tt = idx & 511;
      xs[m][tt] = Xc[((size_t)f*8 + m)*T_ + c*512 + tt];
    }
    if (MODE == 1){
      for (int idx=tid; idx<1024; idx+=256){
        int k = idx >> 9, tt = idx & 511;
        wsm[k][tt] = wts[k*T_ + c*512 + tt];
      }
    }
    __syncthreads();
    for (int t=lane; t<512; t+=64){
      float w0=0.f, w1=0.f;
      if (MODE==1){ w0 = wsm[0][t]; w1 = wsm[1][t]; }
      #pragma unroll
      for (int pi=0; pi<9; ++pi){
        int p = wave + pi*4;
        int m = PMt[p], n = PNt[p];
        float2 av = xs[m][t], bv = xs[n][t];
        float zr = av.x*bv.x + av.y*bv.y;   // a * conj(b)
        float zi = av.y*bv.x - av.x*bv.y;
        if (MODE == 0){ a0r[pi] += zr; a0i[pi] += zi; }
        else { a0r[pi] += w0*zr; a0i[pi] += w0*zi; a1r[pi] += w1*zr; a1i[pi] += w1*zi; }
      }
    }
    __syncthreads();
  }
  const double inv = 1.0 / (double)T_;
  #pragma unroll
  for (int pi=0; pi<9; ++pi){
    int p = wave + pi*4;
    int m = PMt[p], n = PNt[p];
    double r0=a0r[pi], i0=a0i[pi], r1=a1r[pi], i1=a1i[pi];
    for (int off=32; off; off>>=1){
      r0 += __shfl_down(r0, off, 64);
      i0 += __shfl_down(i0, off, 64);
      if (MODE==1){ r1 += __shfl_down(r1, off, 64); i1 += __shfl_down(i1, off, 64); }
    }
    if (lane == 0){
      if (MODE == 0){
        outC[(size_t)f*64 + m*8 + n] = cmk(r0*inv, i0*inv);
        outC[(size_t)f*64 + n*8 + m] = cmk(r0*inv, -i0*inv);
      } else {
        outC[((size_t)0*F_ + f)*64 + m*8 + n] = cmk(r0*inv, i0*inv);
        outC[((size_t)0*F_ + f)*64 + n*8 + m] = cmk(r0*inv, -i0*inv);
        outC[((size_t)1*F_ + f)*64 + m*8 + n] = cmk(r1*inv, i1*inv);
        outC[((size_t)1*F_ + f)*64 + n*8 + m] = cmk(r1*inv, -i1*inv);
      }
    }
  }
}

// Y = W[:, :K] @ X ; per-f |Y|^2 partials
__global__ __launch_bounds__(256) void y_kernel(const float2* __restrict__ Xc, const float2* __restrict__ Wg,
                                                float* __restrict__ r2part, const int* __restrict__ done){
  if (*(volatile const int*)done) return;
  int f = blockIdx.x;
  int t = blockIdx.y*256 + threadIdx.x;
  const float2* Wf = Wg + (size_t)f*64;
  float2 y0; y0.x=0; y0.y=0;
  float2 y1; y1.x=0; y1.y=0;
  #pragma unroll
  for (int m=0;m<8;++m){
    float2 xv = Xc[((size_t)f*8 + m)*T_ + t];
    float2 w0 = Wf[m];
    float2 w1 = Wf[8+m];
    y0.x += w0.x*xv.x - w0.y*xv.y; y0.y += w0.x*xv.y + w0.y*xv.x;
    y1.x += w1.x*xv.x - w1.y*xv.y; y1.y += w1.x*xv.y + w1.y*xv.x;
  }
  r2part[((size_t)f*2+0)*T_ + t] = y0.x*y0.x + y0.y*y0.y;
  r2part[((size_t)f*2+1)*T_ + t] = y1.x*y1.x + y1.y*y1.y;
}

// reduce over f -> w[k,t] = 0.5/sqrt(max(r2,EPS_R))
__global__ __launch_bounds__(256) void rw_kernel(const float* __restrict__ r2part, float* __restrict__ wts,
                                                 const int* __restrict__ done){
  if (*(volatile const int*)done) return;
  int idx = blockIdx.x*256 + threadIdx.x;
  if (idx >= K_*T_) return;
  int k = idx >> 11, t = idx & (T_-1);
  double s = 0;
  for (int f=0; f<F_; ++f) s += (double)r2part[((size_t)f*2+k)*T_ + t];
  double r = sqrt(fmax(s, EPSR));
  wts[idx] = (float)(0.5 / r);
}

// one wave64 per frequency: the per-f IVA update (solves + J) in double
__global__ __launch_bounds__(256) void update_kernel(const cd* __restrict__ Vg, const cd* __restrict__ Cg,
                                                     float2* __restrict__ Wg,
                                                     double* __restrict__ diff2, double* __restrict__ old2,
                                                     const int* __restrict__ done){
  if (*(volatile const int*)done) return;
  int lane = threadIdx.x & 63;
  int f = blockIdx.x*4 + (threadIdx.x >> 6);
  if (f >= F_) return;
  int i = lane >> 3, j = lane & 7;
  float2 wf = Wg[(size_t)f*64 + lane];
  cd Wn = cmk(wf.x, wf.y);
  cd Wold = Wn;
  cd x[8];
  #pragma unroll
  for (int k=0; k<K_; ++k){
    cd Vr = Vg[((size_t)k*F_ + f)*64 + lane];
    if (i == j) Vr.x += REGC;
    // temp = Wn @ Vr
    cd temp = cmk(0,0);
    #pragma unroll
    for (int q=0;q<8;++q) temp = cadd(temp, cmul(shflc(Wn, i*8+q), shflc(Vr, q*8+j)));
    // rhs e_k, replicated across each row's lanes
    cd b = cmk(i==k ? 1.0 : 0.0, 0.0);
    // Gaussian elimination w/ partial pivoting
    for (int p=0; p<8; ++p){
      double pv = (j==p && i>=p) ? cabs2(temp) : -1.0;
      int pidx = i;
      for (int off=32; off; off>>=1){
        double ov = __shfl_xor(pv, off, 64);
        int oi = __shfl_xor(pidx, off, 64);
        if (ov > pv){ pv = ov; pidx = oi; }
      }
      cd tp = shflc(temp, pidx*8 + j);
      cd tq = shflc(temp, p*8 + j);
      cd bp_ = shflc(b, pidx*8 + j);
      cd bq_ = shflc(b, p*8 + j);
      if (i == p){ temp = tp; b = bp_; }
      else if (i == pidx){ temp = tq; b = bq_; }
      cd tip = shflc(temp, i*8 + p);
      cd tpp = shflc(temp, p*8 + p);
      cd tpj = shflc(temp, p*8 + j);
      cd bpr = shflc(b, p*8 + j);
      cd fac = cdiv(tip, tpp);
      if (i > p){ temp = csub(temp, cmul(fac, tpj)); b = csub(b, cmul(fac, bpr)); }
    }
    // back substitution -> x replicated on all lanes
    #pragma unroll
    for (int p=7; p>=0; --p){
      cd s = shflc(b, p*8);
      #pragma unroll
      for (int q=p+1; q<8; ++q){
        cd tpq = shflc(temp, p*8 + q);
        s = csub(s, cmul(tpq, x[q]));
      }
      x[p] = cdiv(s, shflc(temp, p*8 + p));
    }
    cd xi = sel8(x, i), xj = sel8(x, j);
    cd z = cmul(cconj(xi), Vr);
    double dl = z.x*xj.x - z.y*xj.y;  // real(conj(xi)*V*xj)
    for (int off=32; off; off>>=1) dl += __shfl_xor(dl, off, 64);
    double denom = sqrt(dl + EPSR);
    if (i == k){ Wn = cmk(xj.x/denom, -xj.y/denom); }
  }
  // J update: tmp = Wn[:2] @ C, solve 2x2, Wn[K:, :K] = conj(Z^T)
  cd Cc = Cg[(size_t)f*64 + lane];
  cd tmp = cmk(0,0);
  #pragma unroll
  for (int q=0;q<8;++q) tmp = cadd(tmp, cmul(shflc(Wn, i*8+q), shflc(Cc, q*8+j)));
  cd A = shflc(tmp, 0), B = shflc(tmp, 1), C2 = shflc(tmp, 8), D = shflc(tmp, 9);
  cd det = csub(cmul(A,D), cmul(B,C2));
  cd t0 = shflc(tmp, i);       // tmp(0, col=i)
  cd t1 = shflc(tmp, 8 + i);   // tmp(1, col=i)
  cd Z0 = cdiv(csub(cmul(D,t0), cmul(B,t1)), det);
  cd Z1 = cdiv(csub(cmul(A,t1), cmul(C2,t0)), det);
  if (i >= K_ && j < K_){
    cd Z = (j==0) ? Z0 : Z1;
    Wn = cconj(Z);
  }
  double ds = cabs2(csub(Wn, Wold));
  double os = cabs2(Wold);
  for (int off=32; off; off>>=1){
    ds += __shfl_xor(ds, off, 64);
    os += __shfl_xor(os, off, 64);
  }
  if (lane == 0){ diff2[f] = ds; old2[f] = os; }
  float2 wo; wo.x = (float)Wn.x; wo.y = (float)Wn.y;
  Wg[(size_t)f*64 + lane] = wo;
}

__global__ __launch_bounds__(256) void normred_kernel(const double* __restrict__ diff2, const double* __restrict__ old2,
                                                      int* __restrict__ done){
  if (*(volatile const int*)done) return;
  __shared__ double sd[4], so[4];
  double d=0, o=0;
  for (int idx=threadIdx.x; idx<F_; idx+=256){ d += diff2[idx]; o += old2[idx]; }
  for (int off=32; off; off>>=1){ d += __shfl_xor(d, off, 64); o += __shfl_xor(o, off, 64); }
  int w = threadIdx.x >> 6;
  if ((threadIdx.x & 63) == 0){ sd[w] = d; so[w] = o; }
  __syncthreads();
  if (threadIdx.x == 0){
    double td = sd[0]+sd[1]+sd[2]+sd[3];
    double to = so[0]+so[1]+so[2]+so[3];
    double rel = sqrt(td) / fmax(sqrt(to), 1.1920928955078125e-7);
    if (rel < TOLC) *done = 1;
  }
}

// scale[f,k] = row REF_MIC-1 of pinv(W) = W^H (W W^H)^{-1}
__global__ __launch_bounds__(256) void scale_kernel(const float2* __restrict__ Wg, float2* __restrict__ scale){
  int f = blockIdx.x*256 + threadIdx.x;
  if (f >= F_) return;
  cd w0[8], w1[8];
  #pragma unroll
  for (int m=0;m<8;++m){
    float2 a = Wg[(size_t)f*64 + m];     w0[m] = cmk(a.x, a.y);
    float2 b = Wg[(size_t)f*64 + 8 + m]; w1[m] = cmk(b.x, b.y);
  }
  cd G00 = cmk(0,0), G01 = cmk(0,0), G11 = cmk(0,0);
  #pragma unroll
  for (int m=0;m<8;++m){
    G00 = cadd(G00, cmul(w0[m], cconj(w0[m])));
    G01 = cadd(G01, cmul(w0[m], cconj(w1[m])));
    G11 = cadd(G11, cmul(w1[m], cconj(w1[m])));
  }
  cd G10 = cconj(G01);
  cd det = csub(cmul(G00,G11), cmul(G01,G10));
  cd I00 = cdiv(G11, det), I01 = cdiv(cmk(-G01.x,-G01.y), det);
  cd I10 = cdiv(cmk(-G10.x,-G10.y), det), I11 = cdiv(G00, det);
  cd c0 = cconj(w0[0]), c1 = cconj(w1[0]);
  cd s0 = cadd(cmul(c0, I00), cmul(c1, I10));
  cd s1 = cadd(cmul(c0, I01), cmul(c1, I11));
  float2 o0; o0.x=(float)s0.x; o0.y=(float)s0.y;
  float2 o1; o1.x=(float)s1.x; o1.y=(float)s1.y;
  scale[(size_t)f*2 + 0] = o0;
  scale[(size_t)f*2 + 1] = o1;
}

__global__ __launch_bounds__(256) void out_kernel(const float2* __restrict__ Xc, const float2* __restrict__ Wg,
                                                  const float2* __restrict__ scale, float2* __restrict__ out){
  int f = blockIdx.x;
  int t = blockIdx.y*256 + threadIdx.x;
  const float2* Wf = Wg + (size_t)f*64;
  float2 y0; y0.x=0; y0.y=0;
  float2 y1; y1.x=0; y1.y=0;
  #pragma unroll
  for (int m=0;m<8;++m){
    float2 xv = Xc[((size_t)f*8 + m)*T_ + t];
    float2 w0 = Wf[m];
    float2 w1 = Wf[8+m];
    y0.x += w0.x*xv.x - w0.y*xv.y; y0.y += w0.x*xv.y + w0.y*xv.x;
    y1.x += w1.x*xv.x - w1.y*xv.y; y1.y += w1.x*xv.y + w1.y*xv.x;
  }
  float2 s0 = scale[(size_t)f*2 + 0];
  float2 s1 = scale[(size_t)f*2 + 1];
  float2 o0; o0.x = s0.x*y0.x - s0.y*y0.y; o0.y = s0.x*y0.y + s0.y*y0.x;
  float2 o1; o1.x = s1.x*y1.x - s1.y*y1.y; o1.y = s1.x*y1.y + s1.y*y1.x;
  out[((size_t)(0*T_ + t))*F_ + f] = o0;
  out[((size_t)(1*T_ + t))*F_ + f] = o1;
}

extern "C" void kernel_launch(void* const* d_in, const int* in_sizes, int n_in,
                              void* d_out, int out_size, void* d_ws, size_t ws_size,
                              hipStream_t stream) {
  const float2* Xin = (const float2*)d_in[0];
  char* ws = (char*)d_ws;
  size_t off = 0;
  auto alloc = [&](size_t bytes) -> void* {
    void* p = ws + off;
    off += (bytes + 255) & ~(size_t)255;
    return p;
  };
  float2* Xc   = (float2*)alloc((size_t)F_*M_*T_*8);
  cd*     Cm   = (cd*)alloc((size_t)F_*64*16);
  cd*     Vm   = (cd*)alloc((size_t)K_*F_*64*16);
  float2* W    = (float2*)alloc((size_t)F_*64*8);
  float*  r2p  = (float*)alloc((size_t)F_*K_*T_*4);
  float*  wts  = (float*)alloc((size_t)K_*T_*4);
  double* d2   = (double*)alloc((size_t)F_*8);
  double* o2   = (double*)alloc((size_t)F_*8);
  float2* sc   = (float2*)alloc((size_t)F_*K_*8);
  int*    done = (int*)alloc(256);
  if (off > ws_size) return;  // insufficient workspace -> fail visibly

  hipMemsetAsync(done, 0, 4, stream);

  pack_kernel<<<(F_*M_*T_ + 255)/256, 256, 0, stream>>>(Xin, Xc);
  winit_kernel<<<(F_*64 + 255)/256, 256, 0, stream>>>(W);
  cov_kernel<0><<<F_, 256, 0, stream>>>(Xc, nullptr, Cm, done);

  for (int it=0; it<NITER; ++it){
    y_kernel<<<dim3(F_, T_/256), 256, 0, stream>>>(Xc, W, r2p, done);
    rw_kernel<<<(K_*T_ + 255)/256, 256, 0, stream>>>(r2p, wts, done);
    cov_kernel<1><<<F_, 256, 0, stream>>>(Xc, wts, Vm, done);
    update_kernel<<<(F_ + 3)/4, 256, 0, stream>>>(Vm, Cm, W, d2, o2, done);
    normred_kernel<<<1, 256, 0, stream>>>(d2, o2, done);
  }

  scale_kernel<<<(F_ + 255)/256, 256, 0, stream>>>(W, sc);
  out_kernel<<<dim3(F_, T_/256), 256, 0, stream>>>(Xc, W, sc, (float2*)d_out);
}

// Round 2
// 2042.884 us; speedup vs baseline: 1.2178x; 1.2178x over previous
//
#include <hip/hip_runtime.h>

#define F_ 513
#define M_ 8
#define T_ 2048
#define K_ 2
#define NITER 20
#define REGC 1e-6
#define EPSR 1e-10
#define TOLC 1e-5
#define NG 32
#define UPB ((F_ + 3) / 4)

typedef double2 cd;
__device__ __forceinline__ cd cmk(double r, double i){ cd z; z.x=r; z.y=i; return z; }
__device__ __forceinline__ cd cadd(cd a, cd b){ return cmk(a.x+b.x, a.y+b.y); }
__device__ __forceinline__ cd csub(cd a, cd b){ return cmk(a.x-b.x, a.y-b.y); }
__device__ __forceinline__ cd cmul(cd a, cd b){ return cmk(a.x*b.x - a.y*b.y, a.x*b.y + a.y*b.x); }
__device__ __forceinline__ cd cconj(cd a){ return cmk(a.x, -a.y); }
__device__ __forceinline__ cd cdiv(cd a, cd b){
  double d = b.x*b.x + b.y*b.y;
  return cmk((a.x*b.x + a.y*b.y)/d, (a.y*b.x - a.x*b.y)/d);
}
__device__ __forceinline__ double cabs2(cd a){ return a.x*a.x + a.y*a.y; }
__device__ __forceinline__ cd shflc(cd v, int l){
  cd r; r.x = __shfl(v.x, l, 64); r.y = __shfl(v.y, l, 64); return r;
}
__device__ __forceinline__ cd sel8(const cd x[8], int idx){
  cd r = x[0];
  #pragma unroll
  for (int q=1;q<8;++q) if (idx==q) r = x[q];
  return r;
}

// pack X (M,T,F,2) -> Xc (F,M,T) complex, via LDS tile transpose.
// grid (9, 32, 8): f-tile 64, t-tile 64, m
__global__ __launch_bounds__(256) void pack_kernel(const float2* __restrict__ Xin, float2* __restrict__ Xc){
  __shared__ float tr[64][65];
  __shared__ float ti[64][65];
  int f0 = blockIdx.x*64, t0 = blockIdx.y*64, m = blockIdx.z;
  for (int i = threadIdx.x; i < 64*64; i += 256){
    int tl = i >> 6, fl = i & 63;           // lanes -> consecutive f (coalesced read)
    int f = f0 + fl;
    float2 v; v.x = 0.f; v.y = 0.f;
    if (f < F_) v = Xin[((size_t)m*T_ + (t0 + tl))*F_ + f];
    tr[tl][fl] = v.x; ti[tl][fl] = v.y;
  }
  __syncthreads();
  for (int i = threadIdx.x; i < 64*64; i += 256){
    int fl = i >> 6, tl = i & 63;           // lanes -> consecutive t (coalesced write)
    int f = f0 + fl;
    if (f < F_){
      float2 v; v.x = tr[tl][fl]; v.y = ti[tl][fl];
      Xc[((size_t)f*8 + m)*T_ + (t0 + tl)] = v;
    }
  }
}

// W init: diag(1,1,-1,...,-1)
__global__ __launch_bounds__(256) void winit_kernel(float2* __restrict__ W){
  int idx = blockIdx.x*256 + threadIdx.x;
  if (idx >= F_*64) return;
  int l = idx & 63; int i = l>>3, j = l&7;
  float v = (i==j) ? (i < K_ ? 1.f : -1.f) : 0.f;
  float2 o; o.x = v; o.y = 0.f;
  W[idx] = o;
}

__device__ const int PMt[36] = {0,0,0,0,0,0,0,0,1,1,1,1,1,1,1,2,2,2,2,2,2,3,3,3,3,3,4,4,4,4,5,5,5,6,6,7};
__device__ const int PNt[36] = {0,1,2,3,4,5,6,7,1,2,3,4,5,6,7,2,3,4,5,6,7,3,4,5,6,7,4,5,6,7,5,6,7,6,7,7};

// MODE 0: C[f] = X X^H / T ; MODE 1: V[k,f] = sum_t w[k,t] x x^H / T
template<int MODE>
__global__ __launch_bounds__(256) void cov_kernel(const float2* __restrict__ Xc, const float* __restrict__ wts,
                                                  cd* __restrict__ outC, const int* __restrict__ flags){
  if (MODE == 1 && *(volatile const int*)flags) return;
  __shared__ float2 xs[8][512];
  __shared__ float wsm[2][512];
  int f = blockIdx.x;
  int tid = threadIdx.x;
  int wave = tid >> 6, lane = tid & 63;
  double a0r[9], a0i[9], a1r[9], a1i[9];
  #pragma unroll
  for (int pi=0; pi<9; ++pi){ a0r[pi]=0; a0i[pi]=0; a1r[pi]=0; a1i[pi]=0; }
  for (int c=0; c<4; ++c){
    for (int idx=tid; idx<8*256; idx+=256){
      int m = idx >> 8, q = idx & 255;
      ((float4*)&xs[m][0])[q] = ((const float4*)(Xc + ((size_t)f*8 + m)*T_ + c*512))[q];
    }
    if (MODE == 1){
      for (int idx=tid; idx<256; idx+=256){
        int k = idx >> 7, q = idx & 127;
        ((float4*)&wsm[k][0])[q] = ((const float4*)(wts + k*T_ + c*512))[q];
      }
    }
    __syncthreads();
    for (int t=lane; t<512; t+=64){
      float w0=0.f, w1=0.f;
      if (MODE==1){ w0 = wsm[0][t]; w1 = wsm[1][t]; }
      #pragma unroll
      for (int pi=0; pi<9; ++pi){
        int p = wave + pi*4;
        int m = PMt[p], n = PNt[p];
        float2 av = xs[m][t], bv = xs[n][t];
        float zr = av.x*bv.x + av.y*bv.y;
        float zi = av.y*bv.x - av.x*bv.y;
        if (MODE == 0){ a0r[pi] += zr; a0i[pi] += zi; }
        else { a0r[pi] += w0*zr; a0i[pi] += w0*zi; a1r[pi] += w1*zr; a1i[pi] += w1*zi; }
      }
    }
    __syncthreads();
  }
  const double inv = 1.0 / (double)T_;
  #pragma unroll
  for (int pi=0; pi<9; ++pi){
    int p = wave + pi*4;
    int m = PMt[p], n = PNt[p];
    double r0=a0r[pi], i0=a0i[pi], r1=a1r[pi], i1=a1i[pi];
    for (int off=32; off; off>>=1){
      r0 += __shfl_down(r0, off, 64);
      i0 += __shfl_down(i0, off, 64);
      if (MODE==1){ r1 += __shfl_down(r1, off, 64); i1 += __shfl_down(i1, off, 64); }
    }
    if (lane == 0){
      if (MODE == 0){
        outC[(size_t)f*64 + m*8 + n] = cmk(r0*inv, i0*inv);
        outC[(size_t)f*64 + n*8 + m] = cmk(r0*inv, -i0*inv);
      } else {
        outC[((size_t)0*F_ + f)*64 + m*8 + n] = cmk(r0*inv, i0*inv);
        outC[((size_t)0*F_ + f)*64 + n*8 + m] = cmk(r0*inv, -i0*inv);
        outC[((size_t)1*F_ + f)*64 + m*8 + n] = cmk(r1*inv, i1*inv);
        outC[((size_t)1*F_ + f)*64 + n*8 + m] = cmk(r1*inv, -i1*inv);
      }
    }
  }
}

// partial r2 over f-groups: grid (T_/256, NG); part[g][k][t]
__global__ __launch_bounds__(256) void yr_kernel(const float2* __restrict__ Xc, const float2* __restrict__ Wg,
                                                 float* __restrict__ part, const int* __restrict__ flags){
  if (*(volatile const int*)flags) return;
  int g = blockIdx.y;
  int t = blockIdx.x*256 + threadIdx.x;
  float acc0 = 0.f, acc1 = 0.f;
  for (int f = g; f < F_; f += NG){
    const float2* Wf = Wg + (size_t)f*64;
    float2 y0; y0.x=0; y0.y=0;
    float2 y1; y1.x=0; y1.y=0;
    #pragma unroll
    for (int m=0;m<8;++m){
      float2 xv = Xc[((size_t)f*8 + m)*T_ + t];
      float2 w0 = Wf[m];
      float2 w1 = Wf[8+m];
      y0.x += w0.x*xv.x - w0.y*xv.y; y0.y += w0.x*xv.y + w0.y*xv.x;
      y1.x += w1.x*xv.x - w1.y*xv.y; y1.y += w1.x*xv.y + w1.y*xv.x;
    }
    acc0 += y0.x*y0.x + y0.y*y0.y;
    acc1 += y1.x*y1.x + y1.y*y1.y;
  }
  part[((size_t)g*2+0)*T_ + t] = acc0;
  part[((size_t)g*2+1)*T_ + t] = acc1;
}

// wts[k][t] = 0.5 / sqrt(max(sum_g part, EPS_R)); grid 16 x 256
__global__ __launch_bounds__(256) void rw_kernel(const float* __restrict__ part, float* __restrict__ wts,
                                                 const int* __restrict__ flags){
  if (*(volatile const int*)flags) return;
  int v = blockIdx.x*256 + threadIdx.x;
  int k = v >> 11, t = v & (T_-1);
  double s = 0;
  #pragma unroll
  for (int g=0; g<NG; ++g) s += (double)part[((size_t)g*2+k)*T_ + t];
  wts[v] = (float)(0.5 / sqrt(fmax(s, EPSR)));
}

// one wave64 per f; fused convergence reduction via ticket (flags[0]=done, flags[1]=ticket)
__global__ __launch_bounds__(256) void update_kernel(const cd* __restrict__ Vg, const cd* __restrict__ Cg,
                                                     float2* __restrict__ Wg,
                                                     double* __restrict__ dsum, double* __restrict__ osum,
                                                     int* __restrict__ flags){
  if (*(volatile const int*)flags) return;
  int lane = threadIdx.x & 63;
  int w = threadIdx.x >> 6;
  int f = blockIdx.x*4 + w;
  int i = lane >> 3, j = lane & 7;
  double ds = 0.0, os = 0.0;
  if (f < F_){
    float2 wf = Wg[(size_t)f*64 + lane];
    cd Wn = cmk(wf.x, wf.y);
    cd Wold = Wn;
    cd x[8];
    #pragma unroll
    for (int k=0; k<K_; ++k){
      cd Vr = Vg[((size_t)k*F_ + f)*64 + lane];
      if (i == j) Vr.x += REGC;
      cd temp = cmk(0,0);
      #pragma unroll
      for (int q=0;q<8;++q) temp = cadd(temp, cmul(shflc(Wn, i*8+q), shflc(Vr, q*8+j)));
      cd b = cmk(i==k ? 1.0 : 0.0, 0.0);
      for (int p=0; p<8; ++p){
        double pv = (j==p && i>=p) ? cabs2(temp) : -1.0;
        int pidx = i;
        for (int off=32; off; off>>=1){
          double ov = __shfl_xor(pv, off, 64);
          int oi = __shfl_xor(pidx, off, 64);
          if (ov > pv){ pv = ov; pidx = oi; }
        }
        cd tp = shflc(temp, pidx*8 + j);
        cd tq = shflc(temp, p*8 + j);
        cd bp_ = shflc(b, pidx*8 + j);
        cd bq_ = shflc(b, p*8 + j);
        if (i == p){ temp = tp; b = bp_; }
        else if (i == pidx){ temp = tq; b = bq_; }
        cd tip = shflc(temp, i*8 + p);
        cd tpp = shflc(temp, p*8 + p);
        cd tpj = shflc(temp, p*8 + j);
        cd bpr = shflc(b, p*8 + j);
        cd fac = cdiv(tip, tpp);
        if (i > p){ temp = csub(temp, cmul(fac, tpj)); b = csub(b, cmul(fac, bpr)); }
      }
      #pragma unroll
      for (int p=7; p>=0; --p){
        cd s = shflc(b, p*8);
        #pragma unroll
        for (int q=p+1; q<8; ++q){
          cd tpq = shflc(temp, p*8 + q);
          s = csub(s, cmul(tpq, x[q]));
        }
        x[p] = cdiv(s, shflc(temp, p*8 + p));
      }
      cd xi = sel8(x, i), xj = sel8(x, j);
      cd z = cmul(cconj(xi), Vr);
      double dl = z.x*xj.x - z.y*xj.y;
      for (int off=32; off; off>>=1) dl += __shfl_xor(dl, off, 64);
      double denom = sqrt(dl + EPSR);
      if (i == k){ Wn = cmk(xj.x/denom, -xj.y/denom); }
    }
    cd Cc = Cg[(size_t)f*64 + lane];
    cd tmp = cmk(0,0);
    #pragma unroll
    for (int q=0;q<8;++q) tmp = cadd(tmp, cmul(shflc(Wn, i*8+q), shflc(Cc, q*8+j)));
    cd A = shflc(tmp, 0), B = shflc(tmp, 1), C2 = shflc(tmp, 8), D = shflc(tmp, 9);
    cd det = csub(cmul(A,D), cmul(B,C2));
    cd t0 = shflc(tmp, i);
    cd t1 = shflc(tmp, 8 + i);
    cd Z0 = cdiv(csub(cmul(D,t0), cmul(B,t1)), det);
    cd Z1 = cdiv(csub(cmul(A,t1), cmul(C2,t0)), det);
    if (i >= K_ && j < K_){
      cd Z = (j==0) ? Z0 : Z1;
      Wn = cconj(Z);
    }
    ds = cabs2(csub(Wn, Wold));
    os = cabs2(Wold);
    for (int off=32; off; off>>=1){
      ds += __shfl_xor(ds, off, 64);
      os += __shfl_xor(os, off, 64);
    }
    float2 wo; wo.x = (float)Wn.x; wo.y = (float)Wn.y;
    Wg[(size_t)f*64 + lane] = wo;
  }
  // fused norm reduction
  __shared__ double sd[4], so[4];
  __shared__ int lastFlag;
  if (lane == 0){ sd[w] = ds; so[w] = os; }
  __syncthreads();
  if (threadIdx.x == 0){
    dsum[blockIdx.x] = sd[0]+sd[1]+sd[2]+sd[3];
    osum[blockIdx.x] = so[0]+so[1]+so[2]+so[3];
  }
  __threadfence();
  if (threadIdx.x == 0){
    int tk = atomicAdd(&flags[1], 1);
    lastFlag = (tk == UPB-1) ? 1 : 0;
  }
  __syncthreads();
  if (lastFlag && threadIdx.x < 64){
    __threadfence();
    double d=0, o=0;
    for (int idx=lane; idx<UPB; idx+=64){
      d += ((volatile double*)dsum)[idx];
      o += ((volatile double*)osum)[idx];
    }
    for (int off=32; off; off>>=1){ d += __shfl_xor(d, off, 64); o += __shfl_xor(o, off, 64); }
    if (lane == 0){
      flags[1] = 0;
      double rel = sqrt(d) / fmax(sqrt(o), 1.1920928955078125e-7);
      if (rel < TOLC) flags[0] = 1;
    }
  }
}

// scale[f,k] = row 0 of pinv(W) = W^H (W W^H)^{-1}
__global__ __launch_bounds__(256) void scale_kernel(const float2* __restrict__ Wg, float2* __restrict__ scale){
  int f = blockIdx.x*256 + threadIdx.x;
  if (f >= F_) return;
  cd w0[8], w1[8];
  #pragma unroll
  for (int m=0;m<8;++m){
    float2 a = Wg[(size_t)f*64 + m];     w0[m] = cmk(a.x, a.y);
    float2 b = Wg[(size_t)f*64 + 8 + m]; w1[m] = cmk(b.x, b.y);
  }
  cd G00 = cmk(0,0), G01 = cmk(0,0), G11 = cmk(0,0);
  #pragma unroll
  for (int m=0;m<8;++m){
    G00 = cadd(G00, cmul(w0[m], cconj(w0[m])));
    G01 = cadd(G01, cmul(w0[m], cconj(w1[m])));
    G11 = cadd(G11, cmul(w1[m], cconj(w1[m])));
  }
  cd G10 = cconj(G01);
  cd det = csub(cmul(G00,G11), cmul(G01,G10));
  cd I00 = cdiv(G11, det), I01 = cdiv(cmk(-G01.x,-G01.y), det);
  cd I10 = cdiv(cmk(-G10.x,-G10.y), det), I11 = cdiv(G00, det);
  cd c0 = cconj(w0[0]), c1 = cconj(w1[0]);
  cd s0 = cadd(cmul(c0, I00), cmul(c1, I10));
  cd s1 = cadd(cmul(c0, I01), cmul(c1, I11));
  float2 o0; o0.x=(float)s0.x; o0.y=(float)s0.y;
  float2 o1; o1.x=(float)s1.x; o1.y=(float)s1.y;
  scale[(size_t)f*2 + 0] = o0;
  scale[(size_t)f*2 + 1] = o1;
}

// out (K,T,F,2) with scale, via LDS transpose. grid (17, 32): f-tile 32, t-tile 64
__global__ __launch_bounds__(256) void out_kernel(const float2* __restrict__ Xc, const float2* __restrict__ Wg,
                                                  const float2* __restrict__ scale, float2* __restrict__ out){
  __shared__ float re0[32][65], im0[32][65], re1[32][65], im1[32][65];
  int f0 = blockIdx.x*32, t0 = blockIdx.y*64;
  int lane = threadIdx.x & 63, w = threadIdx.x >> 6;
  for (int fl = w; fl < 32; fl += 4){
    int f = f0 + fl;
    if (f < F_){
      const float2* Wf = Wg + (size_t)f*64;
      int t = t0 + lane;
      float2 y0; y0.x=0; y0.y=0;
      float2 y1; y1.x=0; y1.y=0;
      #pragma unroll
      for (int m=0;m<8;++m){
        float2 xv = Xc[((size_t)f*8 + m)*T_ + t];
        float2 w0 = Wf[m];
        float2 w1 = Wf[8+m];
        y0.x += w0.x*xv.x - w0.y*xv.y; y0.y += w0.x*xv.y + w0.y*xv.x;
        y1.x += w1.x*xv.x - w1.y*xv.y; y1.y += w1.x*xv.y + w1.y*xv.x;
      }
      float2 s0 = scale[(size_t)f*2 + 0];
      float2 s1 = scale[(size_t)f*2 + 1];
      re0[fl][lane] = s0.x*y0.x - s0.y*y0.y; im0[fl][lane] = s0.x*y0.y + s0.y*y0.x;
      re1[fl][lane] = s1.x*y1.x - s1.y*y1.y; im1[fl][lane] = s1.x*y1.y + s1.y*y1.x;
    }
  }
  __syncthreads();
  for (int i = threadIdx.x; i < 32*64; i += 256){
    int tl = i >> 5, fl = i & 31;       // lanes -> consecutive f (coalesced write)
    int f = f0 + fl;
    if (f < F_){
      int t = t0 + tl;
      float2 o0; o0.x = re0[fl][tl]; o0.y = im0[fl][tl];
      float2 o1; o1.x = re1[fl][tl]; o1.y = im1[fl][tl];
      out[((size_t)(0*T_ + t))*F_ + f] = o0;
      out[((size_t)(1*T_ + t))*F_ + f] = o1;
    }
  }
}

extern "C" void kernel_launch(void* const* d_in, const int* in_sizes, int n_in,
                              void* d_out, int out_size, void* d_ws, size_t ws_size,
                              hipStream_t stream) {
  const float2* Xin = (const float2*)d_in[0];
  char* ws = (char*)d_ws;
  size_t off = 0;
  auto alloc = [&](size_t bytes) -> void* {
    void* p = ws + off;
    off += (bytes + 255) & ~(size_t)255;
    return p;
  };
  float2* Xc   = (float2*)alloc((size_t)F_*M_*T_*8);
  cd*     Cm   = (cd*)alloc((size_t)F_*64*16);
  cd*     Vm   = (cd*)alloc((size_t)K_*F_*64*16);
  float2* W    = (float2*)alloc((size_t)F_*64*8);
  float*  part = (float*)alloc((size_t)NG*K_*T_*4);
  float*  wts  = (float*)alloc((size_t)K_*T_*4);
  double* dsum = (double*)alloc((size_t)UPB*8);
  double* osum = (double*)alloc((size_t)UPB*8);
  float2* sc   = (float2*)alloc((size_t)F_*K_*8);
  int*    flags= (int*)alloc(256);
  if (off > ws_size) return;

  hipMemsetAsync(flags, 0, 8, stream);

  pack_kernel<<<dim3(9, 32, 8), 256, 0, stream>>>(Xin, Xc);
  winit_kernel<<<(F_*64 + 255)/256, 256, 0, stream>>>(W);
  cov_kernel<0><<<F_, 256, 0, stream>>>(Xc, nullptr, Cm, flags);

  for (int it=0; it<NITER; ++it){
    yr_kernel<<<dim3(T_/256, NG), 256, 0, stream>>>(Xc, W, part, flags);
    rw_kernel<<<(K_*T_ + 255)/256, 256, 0, stream>>>(part, wts, flags);
    cov_kernel<1><<<F_, 256, 0, stream>>>(Xc, wts, Vm, flags);
    update_kernel<<<UPB, 256, 0, stream>>>(Vm, Cm, W, dsum, osum, flags);
  }

  scale_kernel<<<(F_ + 255)/256, 256, 0, stream>>>(W, sc);
  out_kernel<<<dim3(17, 32), 256, 0, stream>>>(Xc, W, sc, (float2*)d_out);
}